// Round 1
// baseline (5041.779 us; speedup 1.0000x reference)
//
#include <hip/hip_runtime.h>

#define NN 40000      // nodes
#define NE 640000     // edges
#define DD 128        // feature dim
#define NG 64         // graphs

// ---------------------------------------------------------------------------
// Edge scatter: for each edge e, msg = relu(h[src[e]] + edge_attr[e]),
// atomically accumulated into agg[dst[e]].  32 threads (one float4 lane
// chunk each) per edge; 8 edges per 256-thread block.
// ---------------------------------------------------------------------------
__global__ __launch_bounds__(256) void scatter_k(
    const float* __restrict__ h, const float* __restrict__ ea,
    const int* __restrict__ src, const int* __restrict__ dst,
    float* __restrict__ agg)
{
    int tid = blockIdx.x * 256 + threadIdx.x;
    int e = tid >> 5;
    if (e >= NE) return;
    int lane = tid & 31;
    int s = src[e];
    int d = dst[e];
    const float4 xv = *(const float4*)(h + (size_t)s * DD + lane * 4);
    const float4 ev = *(const float4*)(ea + (size_t)e * DD + lane * 4);
    float4 m;
    m.x = fmaxf(xv.x + ev.x, 0.0f);
    m.y = fmaxf(xv.y + ev.y, 0.0f);
    m.z = fmaxf(xv.z + ev.z, 0.0f);
    m.w = fmaxf(xv.w + ev.w, 0.0f);
    float* a = agg + (size_t)d * DD + lane * 4;
    unsafeAtomicAdd(a + 0, m.x);   // native global_atomic_add_f32
    unsafeAtomicAdd(a + 1, m.y);
    unsafeAtomicAdd(a + 2, m.z);
    unsafeAtomicAdd(a + 3, m.w);
}

// ---------------------------------------------------------------------------
// Fused GEMM + bias + ReLU:  C = relu((A [+ A2]) @ W + bias)
// M = 40000, N = K = 128.  Block tile 128x128, 256 threads, 8x8 per thread.
// A staged transposed in LDS (k-major) so both A and B fragments load as
// float4 (ds_read_b128, conflict-free / 2-way at worst).
// ---------------------------------------------------------------------------
template <int FUSE>
__global__ __launch_bounds__(256) void mlp_gemm(
    const float* __restrict__ A, const float* __restrict__ A2,
    const float* __restrict__ W, const float* __restrict__ bias,
    float* __restrict__ C)
{
    __shared__ float As[32][132];   // [k][row], +4 pad keeps 16B alignment
    __shared__ float Bs[32][132];   // [k][col]

    const int tid = threadIdx.x;
    const int m0 = blockIdx.x * 128;
    const int tx = tid & 15;        // 16 col groups
    const int ty = tid >> 4;        // 16 row groups
    const int r = ty * 8;
    const int c = tx * 8;

    float acc[8][8];
#pragma unroll
    for (int i = 0; i < 8; ++i)
#pragma unroll
        for (int j = 0; j < 8; ++j) acc[i][j] = 0.0f;

    const int lrow = tid >> 3;      // 0..31  (A loader)
    const int lk4  = tid & 7;       // float4 index in k-chunk
    const int bc4  = tid & 31;      // B loader: col float4
    const int bk   = tid >> 5;      // B loader: k row (8 per pass)

    for (int kc = 0; kc < DD; kc += 32) {
        // ---- stage A tile (128 rows x 32 k), transposed into As[k][row]
#pragma unroll
        for (int p = 0; p < 4; ++p) {
            int row = p * 32 + lrow;
            int gr = m0 + row;
            float4 v = make_float4(0.f, 0.f, 0.f, 0.f);
            if (gr < NN) {
                v = *(const float4*)(A + (size_t)gr * DD + kc + lk4 * 4);
                if (FUSE) {
                    float4 v2 = *(const float4*)(A2 + (size_t)gr * DD + kc + lk4 * 4);
                    v.x += v2.x; v.y += v2.y; v.z += v2.z; v.w += v2.w;
                }
            }
            As[lk4 * 4 + 0][row] = v.x;
            As[lk4 * 4 + 1][row] = v.y;
            As[lk4 * 4 + 2][row] = v.z;
            As[lk4 * 4 + 3][row] = v.w;
        }
        // ---- stage B tile (32 k x 128 cols)
#pragma unroll
        for (int p = 0; p < 4; ++p) {
            int kk = p * 8 + bk;
            float4 v = *(const float4*)(W + (size_t)(kc + kk) * DD + bc4 * 4);
            *(float4*)&Bs[kk][bc4 * 4] = v;
        }
        __syncthreads();

#pragma unroll
        for (int k = 0; k < 32; ++k) {
            float4 a0 = *(const float4*)&As[k][r];
            float4 a1 = *(const float4*)&As[k][r + 4];
            float4 b0 = *(const float4*)&Bs[k][c];
            float4 b1 = *(const float4*)&Bs[k][c + 4];
            float av[8] = {a0.x, a0.y, a0.z, a0.w, a1.x, a1.y, a1.z, a1.w};
            float bv[8] = {b0.x, b0.y, b0.z, b0.w, b1.x, b1.y, b1.z, b1.w};
#pragma unroll
            for (int i = 0; i < 8; ++i)
#pragma unroll
                for (int j = 0; j < 8; ++j)
                    acc[i][j] = fmaf(av[i], bv[j], acc[i][j]);
        }
        __syncthreads();
    }

    // ---- epilogue: bias + relu + store
    float4 bb0 = *(const float4*)(bias + c);
    float4 bb1 = *(const float4*)(bias + c + 4);
    float bv[8] = {bb0.x, bb0.y, bb0.z, bb0.w, bb1.x, bb1.y, bb1.z, bb1.w};
#pragma unroll
    for (int i = 0; i < 8; ++i) {
        int gr = m0 + r + i;
        if (gr < NN) {
            float4 o0, o1;
            o0.x = fmaxf(acc[i][0] + bv[0], 0.0f);
            o0.y = fmaxf(acc[i][1] + bv[1], 0.0f);
            o0.z = fmaxf(acc[i][2] + bv[2], 0.0f);
            o0.w = fmaxf(acc[i][3] + bv[3], 0.0f);
            o1.x = fmaxf(acc[i][4] + bv[4], 0.0f);
            o1.y = fmaxf(acc[i][5] + bv[5], 0.0f);
            o1.z = fmaxf(acc[i][6] + bv[6], 0.0f);
            o1.w = fmaxf(acc[i][7] + bv[7], 0.0f);
            *(float4*)(C + (size_t)gr * DD + c) = o0;
            *(float4*)(C + (size_t)gr * DD + c + 4) = o1;
        }
    }
}

// ---------------------------------------------------------------------------
// Global mean pool, stage 1: segment sums.  batch is sorted, so each thread
// accumulates a run of 16 consecutive nodes in registers and flushes with
// atomics only on graph-id change (~16x fewer atomics).
// ---------------------------------------------------------------------------
__device__ inline void pool_flush(float* __restrict__ out, int g, int lane,
                                  const float4& acc)
{
    float* o = out + (size_t)g * DD + lane * 4;
    unsafeAtomicAdd(o + 0, acc.x);
    unsafeAtomicAdd(o + 1, acc.y);
    unsafeAtomicAdd(o + 2, acc.z);
    unsafeAtomicAdd(o + 3, acc.w);
}

__global__ __launch_bounds__(256) void pool_k(
    const float* __restrict__ h, const int* __restrict__ batch,
    float* __restrict__ out, int* __restrict__ cnt)
{
    int tid = blockIdx.x * 256 + threadIdx.x;
    int grp = tid >> 5;
    int lane = tid & 31;
    int n0 = grp * 16;
    if (n0 >= NN) return;
    int nend = min(n0 + 16, NN);

    float4 acc = make_float4(0.f, 0.f, 0.f, 0.f);
    int gprev = batch[n0];
    int crun = 0;
    for (int n = n0; n < nend; ++n) {
        int g = batch[n];
        if (g != gprev) {
            pool_flush(out, gprev, lane, acc);
            if (lane == 0) atomicAdd(cnt + gprev, crun);
            acc = make_float4(0.f, 0.f, 0.f, 0.f);
            crun = 0;
            gprev = g;
        }
        float4 v = *(const float4*)(h + (size_t)n * DD + lane * 4);
        acc.x += v.x; acc.y += v.y; acc.z += v.z; acc.w += v.w;
        ++crun;
    }
    pool_flush(out, gprev, lane, acc);
    if (lane == 0) atomicAdd(cnt + gprev, crun);
}

__global__ __launch_bounds__(256) void pool_div_k(float* __restrict__ out,
                                                  const int* __restrict__ cnt)
{
    int tid = blockIdx.x * 256 + threadIdx.x;
    if (tid >= NG * DD) return;
    int g = tid / DD;
    float c = fmaxf((float)cnt[g], 1.0f);
    out[tid] = out[tid] / c;
}

// ---------------------------------------------------------------------------
extern "C" void kernel_launch(void* const* d_in, const int* in_sizes, int n_in,
                              void* d_out, int out_size, void* d_ws, size_t ws_size,
                              hipStream_t stream)
{
    const float* x     = (const float*)d_in[0];
    const float* ea    = (const float*)d_in[1];
    const int*   ei    = (const int*)d_in[2];
    const int*   batch = (const int*)d_in[3];
    const float* w1[4], * b1[4], * w2[4], * b2[4];
    for (int l = 0; l < 4; ++l) {
        w1[l] = (const float*)d_in[4 + 4 * l];
        b1[l] = (const float*)d_in[5 + 4 * l];
        w2[l] = (const float*)d_in[6 + 4 * l];
        b2[l] = (const float*)d_in[7 + 4 * l];
    }

    const int* srcp = ei;            // edge_index[0]
    const int* dstp = ei + NE;       // edge_index[1]

    char* ws = (char*)d_ws;
    const size_t hbytes = (size_t)NN * DD * sizeof(float);   // 20.48 MB
    float* agg = (float*)ws;                      // also reused as MLP hidden u
    float* hA  = (float*)(ws + hbytes);
    float* hB  = (float*)(ws + 2 * hbytes);
    int*   cnt = (int*)(ws + 3 * hbytes);

    const int scatter_blocks = (NE * 32) / 256;   // 80000
    const int gemm_blocks = (NN + 127) / 128;     // 313
    const int pool_blocks = ((NN / 16) * 32 + 255) / 256;  // 313

    const float* hcur = x;
    float* bufs[2] = {hA, hB};
    for (int l = 0; l < 4; ++l) {
        hipMemsetAsync(agg, 0, hbytes, stream);
        scatter_k<<<scatter_blocks, 256, 0, stream>>>(hcur, ea, srcp, dstp, agg);
        // u = relu((hcur + agg) @ W1 + b1)  -- written in place over agg
        // (safe: each block reads only the rows it later writes)
        mlp_gemm<1><<<gemm_blocks, 256, 0, stream>>>(hcur, agg, w1[l], b1[l], agg);
        // hnext = relu(relu-output @ W2 + b2)   (outer layer relu fused)
        float* hnext = bufs[l & 1];
        mlp_gemm<0><<<gemm_blocks, 256, 0, stream>>>(agg, nullptr, w2[l], b2[l], hnext);
        hcur = hnext;
    }

    // global mean pool
    hipMemsetAsync(d_out, 0, (size_t)NG * DD * sizeof(float), stream);
    hipMemsetAsync(cnt, 0, NG * sizeof(int), stream);
    pool_k<<<pool_blocks, 256, 0, stream>>>(hcur, batch, (float*)d_out, cnt);
    pool_div_k<<<(NG * DD + 255) / 256, 256, 0, stream>>>((float*)d_out, cnt);
}

// Round 2
// 1142.059 us; speedup vs baseline: 4.4146x; 4.4146x over previous
//
#include <hip/hip_runtime.h>

#define NN 40000      // nodes
#define NE 640000     // edges
#define DD 128        // feature dim
#define NG 64         // graphs

typedef float vf4 __attribute__((ext_vector_type(4)));

// ---------------------------------------------------------------------------
// CSR build (once per launch; edge_index is constant across layers)
// ---------------------------------------------------------------------------
__global__ __launch_bounds__(256) void hist_k(const int* __restrict__ dst,
                                              int* __restrict__ cnt)
{
    int e = blockIdx.x * 256 + threadIdx.x;
    if (e < NE) atomicAdd(&cnt[dst[e]], 1);
}

// single-block exclusive scan of cnt[NN] -> row_ptr[NN+1], also fills cursor
__global__ __launch_bounds__(1024) void scan_k(const int* __restrict__ cnt,
                                               int* __restrict__ row_ptr,
                                               int* __restrict__ cursor)
{
    __shared__ int sm[1024];
    __shared__ int carry_s;
    int t = threadIdx.x;
    if (t == 0) carry_s = 0;
    __syncthreads();
    for (int base = 0; base < NN; base += 1024) {
        int i = base + t;
        int v = (i < NN) ? cnt[i] : 0;
        sm[t] = v;
        __syncthreads();
        for (int off = 1; off < 1024; off <<= 1) {
            int x = (t >= off) ? sm[t - off] : 0;
            __syncthreads();
            sm[t] += x;
            __syncthreads();
        }
        int excl = carry_s + sm[t] - v;
        if (i < NN) { row_ptr[i] = excl; cursor[i] = excl; }
        __syncthreads();
        if (t == 0) carry_s += sm[1023];
        __syncthreads();
    }
    if (t == 0) row_ptr[NN] = carry_s;
}

__global__ __launch_bounds__(256) void fill_k(const int* __restrict__ src,
                                              const int* __restrict__ dst,
                                              int* __restrict__ cursor,
                                              int* __restrict__ ssrc,
                                              int* __restrict__ seid)
{
    int e = blockIdx.x * 256 + threadIdx.x;
    if (e < NE) {
        int d = dst[e];
        int pos = atomicAdd(&cursor[d], 1);
        ssrc[pos] = src[e];
        seid[pos] = e;
    }
}

// ---------------------------------------------------------------------------
// Atomic-free aggregation: 32 lanes per dst node; each lane owns one float4
// chunk of the 128-dim row.  agg[n] = sum_e relu(h[src_e] + ea[eid_e]).
// ---------------------------------------------------------------------------
__global__ __launch_bounds__(256) void gather_k(
    const float* __restrict__ h, const float* __restrict__ ea,
    const int* __restrict__ row_ptr, const int* __restrict__ ssrc,
    const int* __restrict__ seid, float* __restrict__ agg)
{
    int grp = blockIdx.x * 8 + (threadIdx.x >> 5);   // node id
    int lane = threadIdx.x & 31;
    if (grp >= NN) return;
    int beg = row_ptr[grp], end = row_ptr[grp + 1];

    float4 acc = make_float4(0.f, 0.f, 0.f, 0.f);
    int s_next = 0, id_next = 0;
    if (beg < end) { s_next = ssrc[beg]; id_next = seid[beg]; }
    for (int e = beg; e < end; ++e) {
        int s = s_next, id = id_next;
        if (e + 1 < end) { s_next = ssrc[e + 1]; id_next = seid[e + 1]; }
        const float4 xv = *(const float4*)(h + (size_t)s * DD + lane * 4);
        vf4 ev = __builtin_nontemporal_load(
            (const vf4*)(ea + (size_t)id * DD + lane * 4));
        acc.x += fmaxf(xv.x + ev.x, 0.0f);
        acc.y += fmaxf(xv.y + ev.y, 0.0f);
        acc.z += fmaxf(xv.z + ev.z, 0.0f);
        acc.w += fmaxf(xv.w + ev.w, 0.0f);
    }
    *(float4*)(agg + (size_t)grp * DD + lane * 4) = acc;
}

// ---------------------------------------------------------------------------
// Fused GEMM + bias + ReLU:  C = relu((A [+ A2]) @ W + bias)
// M = 40000 (multiple of 64), N = K = 128.  Tile 64x128, 256 thr, 4x8/thread.
// ---------------------------------------------------------------------------
template <int FUSE>
__global__ __launch_bounds__(256) void mlp_gemm(
    const float* __restrict__ A, const float* __restrict__ A2,
    const float* __restrict__ W, const float* __restrict__ bias,
    float* __restrict__ C)
{
    __shared__ float As[32][68];    // [k][row], 64 rows + pad
    __shared__ float Bs[32][132];   // [k][col]

    const int tid = threadIdx.x;
    const int m0 = blockIdx.x * 64;
    const int tx = tid & 15;        // 16 col groups x 8 cols
    const int ty = tid >> 4;        // 16 row groups x 4 rows
    const int r = ty * 4;
    const int c = tx * 8;

    float acc[4][8];
#pragma unroll
    for (int i = 0; i < 4; ++i)
#pragma unroll
        for (int j = 0; j < 8; ++j) acc[i][j] = 0.0f;

    const int lrow = tid >> 3;      // 0..31 (A loader row within half-tile)
    const int lk4  = tid & 7;       // float4 index in k-chunk
    const int bc4  = tid & 31;      // B loader: col float4
    const int bk   = tid >> 5;      // B loader: k row (8 per pass)

    for (int kc = 0; kc < DD; kc += 32) {
        // stage A (64 rows x 32 k) transposed -> As[k][row]
#pragma unroll
        for (int p = 0; p < 2; ++p) {
            int row = p * 32 + lrow;
            float4 v = *(const float4*)(A + (size_t)(m0 + row) * DD + kc + lk4 * 4);
            if (FUSE) {
                float4 v2 = *(const float4*)(A2 + (size_t)(m0 + row) * DD + kc + lk4 * 4);
                v.x += v2.x; v.y += v2.y; v.z += v2.z; v.w += v2.w;
            }
            As[lk4 * 4 + 0][row] = v.x;
            As[lk4 * 4 + 1][row] = v.y;
            As[lk4 * 4 + 2][row] = v.z;
            As[lk4 * 4 + 3][row] = v.w;
        }
        // stage B (32 k x 128 cols)
#pragma unroll
        for (int p = 0; p < 4; ++p) {
            int kk = p * 8 + bk;
            *(float4*)&Bs[kk][bc4 * 4] =
                *(const float4*)(W + (size_t)(kc + kk) * DD + bc4 * 4);
        }
        __syncthreads();

#pragma unroll
        for (int k = 0; k < 32; ++k) {
            float4 a0 = *(const float4*)&As[k][r];
            float4 b0 = *(const float4*)&Bs[k][c];
            float4 b1 = *(const float4*)&Bs[k][c + 4];
            float av[4] = {a0.x, a0.y, a0.z, a0.w};
            float bv[8] = {b0.x, b0.y, b0.z, b0.w, b1.x, b1.y, b1.z, b1.w};
#pragma unroll
            for (int i = 0; i < 4; ++i)
#pragma unroll
                for (int j = 0; j < 8; ++j)
                    acc[i][j] = fmaf(av[i], bv[j], acc[i][j]);
        }
        __syncthreads();
    }

    float4 bb0 = *(const float4*)(bias + c);
    float4 bb1 = *(const float4*)(bias + c + 4);
    float bv[8] = {bb0.x, bb0.y, bb0.z, bb0.w, bb1.x, bb1.y, bb1.z, bb1.w};
#pragma unroll
    for (int i = 0; i < 4; ++i) {
        int gr = m0 + r + i;
        float4 o0, o1;
        o0.x = fmaxf(acc[i][0] + bv[0], 0.0f);
        o0.y = fmaxf(acc[i][1] + bv[1], 0.0f);
        o0.z = fmaxf(acc[i][2] + bv[2], 0.0f);
        o0.w = fmaxf(acc[i][3] + bv[3], 0.0f);
        o1.x = fmaxf(acc[i][4] + bv[4], 0.0f);
        o1.y = fmaxf(acc[i][5] + bv[5], 0.0f);
        o1.z = fmaxf(acc[i][6] + bv[6], 0.0f);
        o1.w = fmaxf(acc[i][7] + bv[7], 0.0f);
        *(float4*)(C + (size_t)gr * DD + c) = o0;
        *(float4*)(C + (size_t)gr * DD + c + 4) = o1;
    }
}

// ---------------------------------------------------------------------------
// Global mean pool (batch sorted -> register runs, flush on graph change)
// ---------------------------------------------------------------------------
__device__ inline void pool_flush(float* __restrict__ out, int g, int lane,
                                  const float4& acc)
{
    float* o = out + (size_t)g * DD + lane * 4;
    unsafeAtomicAdd(o + 0, acc.x);
    unsafeAtomicAdd(o + 1, acc.y);
    unsafeAtomicAdd(o + 2, acc.z);
    unsafeAtomicAdd(o + 3, acc.w);
}

__global__ __launch_bounds__(256) void pool_k(
    const float* __restrict__ h, const int* __restrict__ batch,
    float* __restrict__ out, int* __restrict__ cnt)
{
    int tid = blockIdx.x * 256 + threadIdx.x;
    int grp = tid >> 5;
    int lane = tid & 31;
    int n0 = grp * 16;
    if (n0 >= NN) return;
    int nend = min(n0 + 16, NN);

    float4 acc = make_float4(0.f, 0.f, 0.f, 0.f);
    int gprev = batch[n0];
    int crun = 0;
    for (int n = n0; n < nend; ++n) {
        int g = batch[n];
        if (g != gprev) {
            pool_flush(out, gprev, lane, acc);
            if (lane == 0) atomicAdd(cnt + gprev, crun);
            acc = make_float4(0.f, 0.f, 0.f, 0.f);
            crun = 0;
            gprev = g;
        }
        float4 v = *(const float4*)(h + (size_t)n * DD + lane * 4);
        acc.x += v.x; acc.y += v.y; acc.z += v.z; acc.w += v.w;
        ++crun;
    }
    pool_flush(out, gprev, lane, acc);
    if (lane == 0) atomicAdd(cnt + gprev, crun);
}

__global__ __launch_bounds__(256) void pool_div_k(float* __restrict__ out,
                                                  const int* __restrict__ cnt)
{
    int tid = blockIdx.x * 256 + threadIdx.x;
    if (tid >= NG * DD) return;
    int g = tid / DD;
    float c = fmaxf((float)cnt[g], 1.0f);
    out[tid] = out[tid] / c;
}

// ---------------------------------------------------------------------------
extern "C" void kernel_launch(void* const* d_in, const int* in_sizes, int n_in,
                              void* d_out, int out_size, void* d_ws, size_t ws_size,
                              hipStream_t stream)
{
    const float* x     = (const float*)d_in[0];
    const float* ea    = (const float*)d_in[1];
    const int*   ei    = (const int*)d_in[2];
    const int*   batch = (const int*)d_in[3];
    const float* w1[4], * b1[4], * w2[4], * b2[4];
    for (int l = 0; l < 4; ++l) {
        w1[l] = (const float*)d_in[4 + 4 * l];
        b1[l] = (const float*)d_in[5 + 4 * l];
        w2[l] = (const float*)d_in[6 + 4 * l];
        b2[l] = (const float*)d_in[7 + 4 * l];
    }

    const int* srcp = ei;            // edge_index[0]
    const int* dstp = ei + NE;       // edge_index[1]

    char* ws = (char*)d_ws;
    const size_t hbytes = (size_t)NN * DD * sizeof(float);   // 20.48 MB
    float* agg = (float*)ws;                    // also MLP hidden u (in-place)
    float* hA  = (float*)(ws + hbytes);         // layer output ping buffer
    char*  p   = ws + 2 * hbytes;
    int* cnt_node = (int*)p;            p += ((NN * 4 + 255) & ~255);
    int* row_ptr  = (int*)p;            p += (((NN + 1) * 4 + 255) & ~255);
    int* cursor   = (int*)p;            p += ((NN * 4 + 255) & ~255);
    int* ssrc     = (int*)p;            p += ((NE * 4 + 255) & ~255);
    int* seid     = (int*)p;            p += ((NE * 4 + 255) & ~255);
    int* cntG     = (int*)p;

    const int eblocks    = (NE + 255) / 256;        // 2500
    const int gblocks    = (NN + 7) / 8;            // 5000
    const int gemm_blocks = NN / 64;                // 625
    const int pool_blocks = ((NN / 16) * 32 + 255) / 256;

    // ---- build CSR by dst (once; reused by all 4 layers)
    hipMemsetAsync(cnt_node, 0, NN * sizeof(int), stream);
    hist_k<<<eblocks, 256, 0, stream>>>(dstp, cnt_node);
    scan_k<<<1, 1024, 0, stream>>>(cnt_node, row_ptr, cursor);
    fill_k<<<eblocks, 256, 0, stream>>>(srcp, dstp, cursor, ssrc, seid);

    // ---- 4 GINE layers
    const float* hcur = x;
    for (int l = 0; l < 4; ++l) {
        gather_k<<<gblocks, 256, 0, stream>>>(hcur, ea, row_ptr, ssrc, seid, agg);
        // u = relu((hcur + agg) @ W1 + b1), in place over agg (each block
        // reads only the rows it later writes)
        mlp_gemm<1><<<gemm_blocks, 256, 0, stream>>>(hcur, agg, w1[l], b1[l], agg);
        // hnext = relu(u @ W2 + b2) -> hA (hcur no longer needed after gemm1;
        // gemm2 reads only agg, so writing hA is safe even when hcur == hA)
        mlp_gemm<0><<<gemm_blocks, 256, 0, stream>>>(agg, nullptr, w2[l], b2[l], hA);
        hcur = hA;
    }

    // ---- global mean pool
    hipMemsetAsync(d_out, 0, (size_t)NG * DD * sizeof(float), stream);
    hipMemsetAsync(cntG, 0, NG * sizeof(int), stream);
    pool_k<<<pool_blocks, 256, 0, stream>>>(hcur, batch, (float*)d_out, cntG);
    pool_div_k<<<(NG * DD + 255) / 256, 256, 0, stream>>>((float*)d_out, cntG);
}